// Round 1
// baseline (264.387 us; speedup 1.0000x reference)
//
#include <hip/hip_runtime.h>
#include <math.h>

// OTAM cumulative soft-min DTW distance.
// dists: [Q=200, S=200, L=32, M=32] f32 -> out [Q*S] f32 = cum[31][33].
//
// Per (q,s): padded grid Mp=34 columns. Row 0 = prefix sum. Rows 1..31:
//   v[m] = d[m] + softmin(prev[m-1], v[m-1] [, prev[m] if m==1 or m==33])
// softmin_l(x...) = -0.5 * log(sum exp(-2 x_i))  (lambda = 0.5), computed
// stably as mn - 0.5*log(sum exp(-2*(x_i - mn))).

constexpr int QS = 200 * 200;
constexpr int L = 32;
constexpr int M = 32;

__global__ __launch_bounds__(64) void otam_kernel(const float* __restrict__ dists,
                                                  float* __restrict__ out) {
    int p = blockIdx.x * blockDim.x + threadIdx.x;
    if (p >= QS) return;
    const float* dp = dists + (size_t)p * (L * M);

    float prev[34];
    float rowbuf[32];

    // ---- row 0: cumulative sum of padded row (col 0 and col 33 are pad=0) ----
    {
        const float4* r4 = (const float4*)dp;
#pragma unroll
        for (int i = 0; i < 8; ++i) {
            float4 v = r4[i];
            rowbuf[4 * i + 0] = v.x;
            rowbuf[4 * i + 1] = v.y;
            rowbuf[4 * i + 2] = v.z;
            rowbuf[4 * i + 3] = v.w;
        }
        float acc = 0.f;
        prev[0] = 0.f;
#pragma unroll
        for (int m = 1; m <= 32; ++m) {
            acc += rowbuf[m - 1];
            prev[m] = acc;
        }
        prev[33] = acc;  // pad column: +0
    }

    // ---- rows 1..31: serial soft-min recurrence ----
    for (int l = 1; l < 32; ++l) {
        const float4* r4 = (const float4*)(dp + l * M);
#pragma unroll
        for (int i = 0; i < 8; ++i) {
            float4 v = r4[i];
            rowbuf[4 * i + 0] = v.x;
            rowbuf[4 * i + 1] = v.y;
            rowbuf[4 * i + 2] = v.z;
            rowbuf[4 * i + 3] = v.w;
        }
        float c = 0.f;          // running value v[l][m-1]; v[l][0] = 0
        float left = prev[0];   // prev[m-1] (old row value)
#pragma unroll
        for (int m = 1; m <= 33; ++m) {
            float dm = (m <= 32) ? rowbuf[m - 1] : 0.f;
            float pm1 = left;
            float pm = prev[m];
            bool m3 = (m == 1) || (m == 33);
            float mn = fminf(pm1, c);
            if (m3) mn = fminf(mn, pm);
            float sum = __expf(-2.f * (pm1 - mn)) + __expf(-2.f * (c - mn));
            if (m3) sum += __expf(-2.f * (pm - mn));
            float v = dm + mn - 0.5f * __logf(sum);
            left = prev[m];
            prev[m] = v;
            c = v;
        }
    }

    out[p] = prev[33];
}

extern "C" void kernel_launch(void* const* d_in, const int* in_sizes, int n_in,
                              void* d_out, int out_size, void* d_ws, size_t ws_size,
                              hipStream_t stream) {
    const float* dists = (const float*)d_in[0];
    float* out = (float*)d_out;
    // 40000 problems, one thread each; 64-thread blocks -> 625 blocks,
    // spreads single waves across as many CUs/SIMDs as possible.
    dim3 grid((QS + 63) / 64);
    dim3 block(64);
    hipLaunchKernelGGL(otam_kernel, grid, block, 0, stream, dists, out);
}

// Round 2
// 253.089 us; speedup vs baseline: 1.0446x; 1.0446x over previous
//
#include <hip/hip_runtime.h>
#include <math.h>

// OTAM cumulative soft-min DTW, wavefront (anti-diagonal) parallel version.
// dists: [Q=200, S=200, L=32, M=32] f32 -> out [40000] f32 = cum[31][33].
//
// DP grid: rows l in [0,32), padded cols m in [0,34). Col 0 == 0 always.
// Row 0: cumsum. Rows 1..31:
//   v[l][m] = dpad[l][m] + softmin_0.5(prev[m-1], v[l][m-1] [, prev[m] if m==1||m==33])
// softmin computed stably: mn - 0.5*log(sum exp(-2(x-mn))) — the term equal to
// mn contributes exp(0)=1, so only the non-min terms need an exp.
//
// Mapping: lane l (within a 32-lane half-wave) owns row l. Step t computes
// cell (l, m=t-l). Dependencies land on earlier steps:
//   (l, m-1)   = own value from step t-1            (register)
//   (l-1, m-1) = lane l-1's value from step t-2      (shfl result of step t-1)
//   (l-1, m)   = lane l-1's value from step t-1      (shfl result of step t)
// 65 steps total (t=1..64); lane 31 finishes cell (31,33) at t=64.

constexpr int QS = 40000;
constexpr int PPB = 8;  // problems per 256-thread block (2 per wave)

__global__ __launch_bounds__(256) void otam_wavefront(const float* __restrict__ dists,
                                                      float* __restrict__ out) {
    __shared__ float lds[PPB * 1024];  // 8 problems x 32x32, unpadded stride 32
                                       // (diagonal read addr = 32l + (t-1-l) is
                                       //  conflict-free across a 32-lane group)
    const int tid = threadIdx.x;
    const int blockP0 = blockIdx.x * PPB;

    // ---- stage 8 problems into LDS, fully coalesced float4 ----
    {
        const float4* src = (const float4*)(dists + (size_t)blockP0 * 1024);
        float4* dst = (float4*)lds;
#pragma unroll
        for (int i = 0; i < 8; ++i)
            dst[tid + 256 * i] = src[tid + 256 * i];
    }
    __syncthreads();

    const int lane = tid & 63;
    const int sub  = lane >> 5;          // which half-wave (0/1)
    const int l    = lane & 31;          // my DP row
    const int pl   = (tid >> 6) * 2 + sub;  // local problem index
    const float* dp = lds + pl * 1024 + l * 32;  // my row of dpad (unpadded cols 1..32)

    float myval = 0.f;   // v[l][m-1] running value; also holds col-0 = 0 pre-start
    float pm1   = 0.f;   // prev_row[m-1] (shfl result from previous step)

#pragma unroll 4
    for (int t = 1; t <= 64; ++t) {
        float pm = __shfl_up(myval, 1, 32);  // prev_row[m] = lane l-1's last value
        int m = t - l;
        // dpad[l][m]: real data for m in [1,32], 0 for m==33 (and don't-care else)
        int mi = m - 1;
        mi = mi < 0 ? 0 : (mi > 31 ? 31 : mi);   // clamp so the LDS read stays in bounds
        float dm = (m >= 1 && m <= 32) ? dp[mi] : 0.f;

        float nv;
        if (l == 0) {
            nv = myval + dm;  // row 0: cumulative sum (m==33 adds 0)
        } else {
            bool m3 = (m == 1) || (m == 33);
            float mn = fminf(pm1, myval);
            mn = m3 ? fminf(mn, pm) : mn;
            float s = __expf(-2.f * (pm1 - mn)) + __expf(-2.f * (myval - mn));
            s += m3 ? __expf(-2.f * (pm - mn)) : 0.f;
            nv = dm + mn - 0.5f * __logf(s);
        }
        bool active = (m >= 1) && (m <= 33);
        myval = active ? nv : myval;
        pm1 = pm;
    }

    if (l == 31) out[blockP0 + pl] = myval;
}

extern "C" void kernel_launch(void* const* d_in, const int* in_sizes, int n_in,
                              void* d_out, int out_size, void* d_ws, size_t ws_size,
                              hipStream_t stream) {
    const float* dists = (const float*)d_in[0];
    float* out = (float*)d_out;
    dim3 grid(QS / PPB);   // 5000 blocks
    dim3 block(256);
    hipLaunchKernelGGL(otam_wavefront, grid, block, 0, stream, dists, out);
}

// Round 3
// 226.512 us; speedup vs baseline: 1.1672x; 1.1173x over previous
//
#include <hip/hip_runtime.h>
#include <math.h>

// OTAM cumulative soft-min DTW, wavefront-parallel, hardware transcendentals.
// dists: [200,200,32,32] f32 -> out[40000] f32 = cum[31][33].
//
// Mapping (round-2): lane l of a 32-lane half-wave owns DP row l; step t
// computes cell (l, m=t-l). prev-row values arrive via a 1-lane wave shift:
//   pm  (prev_row[m])   = shift of lane l-1's value after step t-1
//   pm1 (prev_row[m-1]) = pm from the previous step
// Softmin always 3-term: third input selected to BIG (=> exp2 -> 0) unless
// m==1 || m==33. Lane 0 (row-0 cumsum) forces pm1=x3=BIG so the softmin
// degenerates to v = d + c exactly.
//   softmin = mn + C2*log2( 2^{K(pm1-mn)} + 2^{K(c-mn)} + 2^{K(x3-mn)} )
//   K = -2/ln2, C2 = -ln2/2   (lambda = 0.5)

constexpr int QS = 40000;
constexpr int PPB = 8;  // problems per 256-thread block (2 per wave)

__device__ __forceinline__ float wave_shr1(float v) {
    // v_mov_b32 dpp wave_shr:1 — lane i gets lane i-1; lane 0 gets 0.
    // Lane 32 gets lane 31 (cross-half) — harmless: l==0 never uses pm.
    int r = __builtin_amdgcn_update_dpp(0, __builtin_bit_cast(int, v),
                                        0x138 /*wave_shr:1*/, 0xF, 0xF, true);
    return __builtin_bit_cast(float, r);
}

__global__ __launch_bounds__(256) void otam_wavefront(const float* __restrict__ dists,
                                                      float* __restrict__ out) {
    __shared__ float lds[PPB * 1024];  // 8 x 32x32, stride 32 (diag reads: 2-way
                                       // half-vs-half aliasing only — free)
    const int tid = threadIdx.x;
    const int blockP0 = blockIdx.x * PPB;

    // stage 8 problems, coalesced float4
    {
        const float4* src = (const float4*)(dists + (size_t)blockP0 * 1024);
        float4* dst = (float4*)lds;
#pragma unroll
        for (int i = 0; i < 8; ++i)
            dst[tid + 256 * i] = src[tid + 256 * i];
    }
    __syncthreads();

    const int lane = tid & 63;
    const int l = lane & 31;
    const int pl = (tid >> 6) * 2 + (lane >> 5);
    const bool l0 = (l == 0);
    // LDS index for step t: pl*1024 + 32*l + (m-1) = [pl*1024 + 31*l] + (t-1)
    // -> lane-constant base, immediate offset per unrolled step.
    const float* base = lds + pl * 1024 + 31 * l;

    const float BIG = 1e30f;
    const float K = -2.8853900817779268f;    // -2/ln2
    const float C2 = -0.34657359027997264f;  // -ln2/2

    float myval = 0.f;                // v[l][m-1]; stays 0 until lane activates
    float pm1 = l0 ? BIG : 0.f;       // prev_row[m-1]

#pragma unroll
    for (int t = 1; t <= 64; ++t) {
        float pm = wave_shr1(myval);
        int m = t - l;
        // t==64: every lane has m>=33 -> no real d needed; skipping the read
        // also keeps the max LDS index at 8191.
        float dval = (t < 64) ? base[t - 1] : 0.f;
        float dm = ((unsigned)(m - 1) < 32u) ? dval : 0.f;
        bool m3 = (m == 1) || (m == 33);
        float x3 = (m3 && !l0) ? pm : BIG;
        float p1 = l0 ? BIG : pm1;
        float mn = fminf(fminf(p1, myval), x3);
        float nkmn = -K * mn;
        float e1 = __builtin_amdgcn_exp2f(fmaf(K, p1, nkmn));
        float e2 = __builtin_amdgcn_exp2f(fmaf(K, myval, nkmn));
        float e3 = __builtin_amdgcn_exp2f(fmaf(K, x3, nkmn));
        float s = e1 + e2 + e3;
        float v = fmaf(C2, __builtin_amdgcn_logf(s), dm + mn);
        bool active = ((unsigned)(m - 1) < 33u);
        myval = active ? v : myval;
        pm1 = pm;
    }

    if (l == 31) out[blockP0 + pl] = myval;
}

extern "C" void kernel_launch(void* const* d_in, const int* in_sizes, int n_in,
                              void* d_out, int out_size, void* d_ws, size_t ws_size,
                              hipStream_t stream) {
    const float* dists = (const float*)d_in[0];
    float* out = (float*)d_out;
    dim3 grid(QS / PPB);  // 5000 blocks
    dim3 block(256);
    hipLaunchKernelGGL(otam_wavefront, grid, block, 0, stream, dists, out);
}